// Round 1
// baseline (358.496 us; speedup 1.0000x reference)
//
#include <hip/hip_runtime.h>

// Problem constants (from reference)
#define B_   8
#define CIN  128
#define CKEY 256   // N_HEADS*HEAD_DIM key channels
#define NH   8
#define HOUT 32    // OUT_CH / N_HEADS
#define CPH  288   // softmax length per head (2304/8)
#define H_   64
#define W_   64
#define HW   4096

// ---------------------------------------------------------------------------
// Kernel 1: 1x1 conv  key[b][o][h][w] = sum_i wk[o][i]*x[b][i][h][w] + bk[o]
// grid = 8*64*4 blocks: (b, h, quarter-of-channels); block = 256 thr = 4 waves
// wave og handles 16 channels, lane = x  (coalesced x loads & key stores)
// ---------------------------------------------------------------------------
__global__ __launch_bounds__(256) void conv1x1_kernel(
    const float* __restrict__ x, const float* __restrict__ wk,
    const float* __restrict__ bk, float* __restrict__ key)
{
  const int bid  = blockIdx.x;
  const int b    = bid >> 8;          // 4*64 blocks per batch
  const int h    = (bid >> 2) & 63;
  const int q    = bid & 3;
  const int lane = threadIdx.x & 63;
  const int og   = __builtin_amdgcn_readfirstlane((int)(threadIdx.x >> 6));
  const int o0   = q * 64 + og * 16;  // first of this thread's 16 channels

  const float* xp = x + (b * CIN) * HW + h * W_ + lane;

  float acc[16];
#pragma unroll
  for (int j = 0; j < 16; ++j) acc[j] = bk[o0 + j];

  for (int ic = 0; ic < 4; ++ic) {     // 4 chunks of 32 input channels
    float xv[32];
#pragma unroll
    for (int ii = 0; ii < 32; ++ii)
      xv[ii] = xp[(ic * 32 + ii) * HW];          // coalesced along lane
#pragma unroll
    for (int j = 0; j < 16; ++j) {
      const float* wr = wk + (o0 + j) * CIN + ic * 32;  // wave-uniform
#pragma unroll
      for (int ii = 0; ii < 32; ++ii)
        acc[j] = fmaf(wr[ii], xv[ii], acc[j]);
    }
  }

#pragma unroll
  for (int j = 0; j < 16; ++j)
    key[(b * CKEY + o0 + j) * HW + h * W_ + lane] = acc[j];  // coalesced
}

// ---------------------------------------------------------------------------
// Kernel 2: head-interleaved softmax + memory matvec.
// For head m, softmax index t: unfold channel u = 8t+m, cch=u/9, p=u%9,
// logit = key[b][cch][h+p/3-1][x+p%3-1]  (0 outside — zero-pad participates!)
// out[b][m*32+i][h][x] = sum_t softmax_t * mem[m][t][i]
// grid = 8*64 blocks (b,h); block = 512 thr = 8 waves; wave = head, lane = x
// mem[m][t][:] address is wave-uniform -> scalar/broadcast fetch, 128B per t
// ---------------------------------------------------------------------------
__global__ __launch_bounds__(512) void attn_out_kernel(
    const float* __restrict__ key, const float* __restrict__ mem,
    float* __restrict__ out)
{
  const int bid = blockIdx.x;
  const int b   = bid >> 6;
  const int h   = bid & 63;
  const int xw  = threadIdx.x & 63;
  const int m   = __builtin_amdgcn_readfirstlane((int)(threadIdx.x >> 6));

  const float* kb = key + (long)b * CKEY * HW;

  // ---- pass A: running max over the 288 logits (incl. zero-pad entries)
  float mx = -3.0e38f;
  {
    int ch = m;
    for (int t = 0; t < CPH; ++t, ch += 8) {
      unsigned u   = (unsigned)ch;
      unsigned cch = u / 9u;              // magic-mul div
      unsigned p   = u - cch * 9u;
      int y  = h  + (int)(p / 3u) - 1;
      int xx = xw + (int)(p % 3u) - 1;
      float v = 0.0f;
      if (((unsigned)y < 64u) && ((unsigned)xx < 64u))
        v = kb[cch * HW + (unsigned)y * W_ + (unsigned)xx];
      mx = fmaxf(mx, v);
    }
  }

  // ---- pass B: exp, sum, and 32-wide weighted accumulate
  float acc[HOUT];
#pragma unroll
  for (int i = 0; i < HOUT; ++i) acc[i] = 0.0f;
  float sum = 0.0f;
  const float* mb = mem + m * (CPH * HOUT);
  {
    int ch = m;
    for (int t = 0; t < CPH; ++t, ch += 8) {
      unsigned u   = (unsigned)ch;
      unsigned cch = u / 9u;
      unsigned p   = u - cch * 9u;
      int y  = h  + (int)(p / 3u) - 1;
      int xx = xw + (int)(p % 3u) - 1;
      float v = 0.0f;
      if (((unsigned)y < 64u) && ((unsigned)xx < 64u))
        v = kb[cch * HW + (unsigned)y * W_ + (unsigned)xx];
      float wt = __expf(v - mx);
      sum += wt;
      const float* mr = mb + t * HOUT;    // wave-uniform address
#pragma unroll
      for (int i = 0; i < HOUT; ++i)
        acc[i] = fmaf(wt, mr[i], acc[i]);
    }
  }

  const float inv = 1.0f / sum;
  float* ob = out + ((long)(b * NH + m) * HOUT) * HW + h * W_ + xw;
#pragma unroll
  for (int i = 0; i < HOUT; ++i)
    ob[i * HW] = acc[i] * inv;            // coalesced along lane
}

extern "C" void kernel_launch(void* const* d_in, const int* in_sizes, int n_in,
                              void* d_out, int out_size, void* d_ws, size_t ws_size,
                              hipStream_t stream) {
  const float* x   = (const float*)d_in[0];
  const float* wk  = (const float*)d_in[1];
  const float* bk  = (const float*)d_in[2];
  const float* mem = (const float*)d_in[3];
  float* key = (float*)d_ws;   // 8*256*4096*4 = 33.5 MB scratch

  conv1x1_kernel<<<dim3(B_ * 64 * 4), dim3(256), 0, stream>>>(x, wk, bk, key);
  attn_out_kernel<<<dim3(B_ * 64), dim3(512), 0, stream>>>(key, mem, (float*)d_out);
}

// Round 2
// 292.962 us; speedup vs baseline: 1.2237x; 1.2237x over previous
//
#include <hip/hip_runtime.h>

// Problem constants (from reference)
#define B_   8
#define CIN  128
#define CKEY 256   // N_HEADS*HEAD_DIM key channels
#define NH   8
#define HOUT 32    // OUT_CH / N_HEADS
#define CPH  288   // softmax length per head (2304/8)
#define H_   64
#define W_   64
#define HW   4096
#define ROWP 66    // padded row length
#define HWP  4356  // 66*66 padded plane

// ---------------------------------------------------------------------------
// Kernel 0: zero the 1-px border of each padded key plane.
// keyp layout: [b][c][66][66], interior (rows 1..64, cols 1..64) = key_map.
// grid = 8*256 planes, 320 threads (260 border elems).
// ---------------------------------------------------------------------------
__global__ __launch_bounds__(320) void border_zero_kernel(float* __restrict__ keyp)
{
  const int plane = blockIdx.x;            // b*256 + c
  const int e = threadIdx.x;
  if (e >= 260) return;
  int r, cc;
  if (e < 66)       { r = 0;       cc = e; }
  else if (e < 132) { r = 65;      cc = e - 66; }
  else if (e < 196) { r = e - 131; cc = 0; }        // rows 1..64, col 0
  else              { r = e - 195; cc = 65; }       // rows 1..64, col 65
  keyp[(size_t)plane * HWP + r * ROWP + cc] = 0.0f;
}

// ---------------------------------------------------------------------------
// Kernel 1: 1x1 conv into padded layout.
// grid = 8*64 blocks (b,h); 512 thr = 8 waves; wave w -> out-ch [32w,32w+32),
// lane = x. x loads coalesced & read exactly once per block (8 waves share via
// L1). Weights are wave-uniform -> scalar s_load. x chunks double-buffered.
// ---------------------------------------------------------------------------
__global__ __launch_bounds__(512) void conv1x1_pad_kernel(
    const float* __restrict__ x, const float* __restrict__ wk,
    const float* __restrict__ bk, float* __restrict__ keyp)
{
  const int bid  = blockIdx.x;
  const int b    = bid >> 6;
  const int h    = bid & 63;
  const int lane = threadIdx.x & 63;
  const int wv   = __builtin_amdgcn_readfirstlane((int)(threadIdx.x >> 6));
  const int o0   = wv * 32;

  const float* xp = x + (size_t)b * CIN * HW + h * W_ + lane;

  float acc[32];
#pragma unroll
  for (int j = 0; j < 32; ++j) acc[j] = bk[o0 + j];

  float xv[2][8];
#pragma unroll
  for (int ii = 0; ii < 8; ++ii) xv[0][ii] = xp[ii * HW];

#pragma unroll
  for (int c = 0; c < 16; ++c) {           // 16 chunks of 8 input channels
    const int cur = c & 1;
    if (c < 15) {
#pragma unroll
      for (int ii = 0; ii < 8; ++ii)
        xv[cur ^ 1][ii] = xp[((c + 1) * 8 + ii) * HW];   // prefetch next chunk
    }
#pragma unroll
    for (int j = 0; j < 32; ++j) {
      const float* wr = wk + (o0 + j) * CIN + c * 8;     // uniform -> s_load
#pragma unroll
      for (int ii = 0; ii < 8; ++ii)
        acc[j] = fmaf(wr[ii], xv[cur][ii], acc[j]);
    }
  }

  float* kp = keyp + ((size_t)(b * CKEY + o0) * HWP) + (h + 1) * ROWP + 1 + lane;
#pragma unroll
  for (int j = 0; j < 32; ++j)
    kp[(size_t)j * HWP] = acc[j];          // coalesced (64 consecutive)
}

// ---------------------------------------------------------------------------
// Kernel 2: single-pass (no max-subtraction) softmax + memory matvec.
// Head m, softmax idx t: u=8t+m, cch=u/9, p=u%9, logit=keyp[cch][h+dy][x+dx]
// (zero border already materialized -> unconditional load).
// All of u/cch/p/dy/dx are wave-uniform -> SALU; vector addr is loop-invariant.
// t grouped by 8 so 8 gathers are in flight per wave.
// grid = 8*64 (b,h); 512 thr = 8 waves; wave = head, lane = x.
// ---------------------------------------------------------------------------
__global__ __launch_bounds__(512) void attn_out_kernel(
    const float* __restrict__ keyp, const float* __restrict__ mem,
    float* __restrict__ out)
{
  const int bid = blockIdx.x;
  const int b   = bid >> 6;
  const int h   = bid & 63;
  const int xw  = threadIdx.x & 63;
  const int m   = __builtin_amdgcn_readfirstlane((int)(threadIdx.x >> 6));

  const float* kb = keyp + (size_t)b * CKEY * HWP + (h + 1) * ROWP + (xw + 1);
  const float* mb = mem + m * (CPH * HOUT);

  float acc[HOUT];
#pragma unroll
  for (int i = 0; i < HOUT; ++i) acc[i] = 0.0f;
  float sum = 0.0f;

  for (int tg = 0; tg < CPH; tg += 8) {
    float v[8];
#pragma unroll
    for (int k = 0; k < 8; ++k) {
      const int u   = 8 * (tg + k) + m;    // uniform
      const int cch = u / 9;               // uniform SALU magic-div
      const int p   = u - 9 * cch;
      const int dy  = p / 3 - 1;
      const int dx  = p % 3 - 1;
      v[k] = kb[cch * HWP + dy * ROWP + dx];   // 8 loads in flight
    }
#pragma unroll
    for (int k = 0; k < 8; ++k) {
      const float wt = __expf(v[k]);       // exp(logit); no max needed
      sum += wt;
      const float* mr = mb + (tg + k) * HOUT;  // uniform -> s_load rows
#pragma unroll
      for (int i = 0; i < HOUT; ++i)
        acc[i] = fmaf(wt, mr[i], acc[i]);
    }
  }

  const float inv = 1.0f / sum;
  float* ob = out + ((size_t)(b * NH + m) * HOUT) * HW + h * W_ + xw;
#pragma unroll
  for (int i = 0; i < HOUT; ++i)
    ob[(size_t)i * HW] = acc[i] * inv;     // coalesced
}

extern "C" void kernel_launch(void* const* d_in, const int* in_sizes, int n_in,
                              void* d_out, int out_size, void* d_ws, size_t ws_size,
                              hipStream_t stream) {
  const float* x   = (const float*)d_in[0];
  const float* wk  = (const float*)d_in[1];
  const float* bk  = (const float*)d_in[2];
  const float* mem = (const float*)d_in[3];
  float* keyp = (float*)d_ws;   // 8*256*66*66*4 = 35.7 MB padded scratch

  border_zero_kernel<<<dim3(B_ * CKEY), dim3(320), 0, stream>>>(keyp);
  conv1x1_pad_kernel<<<dim3(B_ * 64), dim3(512), 0, stream>>>(x, wk, bk, keyp);
  attn_out_kernel<<<dim3(B_ * 64), dim3(512), 0, stream>>>(keyp, mem, (float*)d_out);
}

// Round 3
// 221.067 us; speedup vs baseline: 1.6217x; 1.3252x over previous
//
#include <hip/hip_runtime.h>

// Problem constants (from reference)
#define B_   8
#define CIN  128
#define CKEY 256   // N_HEADS*HEAD_DIM key channels
#define NH   8
#define HOUT 32    // OUT_CH / N_HEADS
#define CPH  288   // softmax length per head (2304/8)
#define H_   64
#define W_   64
#define HW   4096
#define ROWP 66    // padded row length
#define HWP  4356  // 66*66 padded plane

// ---------------------------------------------------------------------------
// Kernel W: transpose wk[och][ic] -> wT[ic][och] so conv weight loads are
// coalesced vector loads with lane = och. 32K elements, trivial.
// ---------------------------------------------------------------------------
__global__ __launch_bounds__(256) void wtrans_kernel(
    const float* __restrict__ wk, float* __restrict__ wT)
{
  const int ic  = blockIdx.x;     // 128
  const int och = threadIdx.x;    // 256
  wT[ic * CKEY + och] = wk[och * CIN + ic];
}

// ---------------------------------------------------------------------------
// Kernel 0: zero the 1-px border of each padded key plane.
// ---------------------------------------------------------------------------
__global__ __launch_bounds__(320) void border_zero_kernel(float* __restrict__ keyp)
{
  const int plane = blockIdx.x;            // b*256 + c
  const int e = threadIdx.x;
  if (e >= 260) return;
  int r, cc;
  if (e < 66)       { r = 0;       cc = e; }
  else if (e < 132) { r = 65;      cc = e - 66; }
  else if (e < 196) { r = e - 131; cc = 0; }
  else              { r = e - 195; cc = 65; }
  keyp[(size_t)plane * HWP + r * ROWP + cc] = 0.0f;
}

// ---------------------------------------------------------------------------
// Kernel 1: 1x1 conv, lane = out-channel mapping.
// grid = 8 * 256 blocks: (b, 16-pixel group). block = 256 thr = 4 waves;
// thread t -> och = t (wave w covers och 64w..64w+63), all 256 och per block.
// Per ic: weight = coalesced vector load from wT (L2-resident);
//         16 pixel x-values are wave-uniform -> s_load_dwordx4 (1 load : 16 FMA).
// 2048 blocks x 4 waves = 8192 waves = 8/SIMD (vs 4 before).
// Store through a stride-17-padded LDS transpose so global stores are
// 16-px-contiguous per 16 lanes (4 x 64B segments per store instr).
// ---------------------------------------------------------------------------
__global__ __launch_bounds__(256, 8) void conv1x1_v3(
    const float* __restrict__ x, const float* __restrict__ wT,
    const float* __restrict__ bk, float* __restrict__ keyp)
{
  __shared__ float tile[CKEY * 17];        // 17408 B; stride 17 kills conflicts

  const int t   = threadIdx.x;             // 0..255; och == t
  const int bid = blockIdx.x;
  const int b   = bid >> 8;                // 256 pixel-groups per batch
  const int pg  = bid & 255;               // 16-px group: h = pg>>2, col0=(pg&3)*16
  const int px0 = pg * 16;

  const float* xb = x + (size_t)b * CIN * HW + px0;   // uniform base (SGPR)
  const float* wp = wT + t;

  float acc[16];
#pragma unroll
  for (int p = 0; p < 16; ++p) acc[p] = 0.0f;

#pragma unroll 4
  for (int ic = 0; ic < CIN; ++ic) {
    const float w = wp[(size_t)ic * CKEY];            // coalesced across lanes
    const float4* xr = (const float4*)(xb + (size_t)ic * HW);  // uniform
    const float4 x0 = xr[0], x1 = xr[1], x2 = xr[2], x3 = xr[3];
    acc[ 0] = fmaf(w, x0.x, acc[ 0]);  acc[ 1] = fmaf(w, x0.y, acc[ 1]);
    acc[ 2] = fmaf(w, x0.z, acc[ 2]);  acc[ 3] = fmaf(w, x0.w, acc[ 3]);
    acc[ 4] = fmaf(w, x1.x, acc[ 4]);  acc[ 5] = fmaf(w, x1.y, acc[ 5]);
    acc[ 6] = fmaf(w, x1.z, acc[ 6]);  acc[ 7] = fmaf(w, x1.w, acc[ 7]);
    acc[ 8] = fmaf(w, x2.x, acc[ 8]);  acc[ 9] = fmaf(w, x2.y, acc[ 9]);
    acc[10] = fmaf(w, x2.z, acc[10]);  acc[11] = fmaf(w, x2.w, acc[11]);
    acc[12] = fmaf(w, x3.x, acc[12]);  acc[13] = fmaf(w, x3.y, acc[13]);
    acc[14] = fmaf(w, x3.z, acc[14]);  acc[15] = fmaf(w, x3.w, acc[15]);
  }

  const float bias = bk[t];                // coalesced
#pragma unroll
  for (int p = 0; p < 16; ++p)
    tile[t * 17 + p] = acc[p] + bias;      // banks 17*lane % 32: all distinct
  __syncthreads();

  // store: iteration j covers och = (t>>4)+16j for px = t&15 (coalesced 16-px runs)
  const int px    = t & 15;
  const int ochr0 = t >> 4;
  const int h     = pg >> 2;
  const int base_pix = (h + 1) * ROWP + (pg & 3) * 16 + 1 + px;
#pragma unroll
  for (int j = 0; j < 16; ++j) {
    const int ochr = ochr0 + 16 * j;
    keyp[((size_t)(b * CKEY + ochr)) * HWP + base_pix] = tile[ochr * 17 + px];
  }
}

// ---------------------------------------------------------------------------
// Kernel 2: softmax (no max-subtraction) + memory matvec, split-K by 2.
// grid = 8*64*2 blocks; block 512 thr = 8 waves = (4 heads x 2 k-halves);
// head m = 4*(bid&1) + (wv&3), lane = x. 8192 waves = 8/SIMD.
// Partial (sum, acc) of the two k-halves combine exactly (shift-free softmax).
// ---------------------------------------------------------------------------
__global__ __launch_bounds__(512, 8) void attn_out_v3(
    const float* __restrict__ keyp, const float* __restrict__ mem,
    float* __restrict__ out)
{
  __shared__ float red[4 * 33 * 64];       // [head][acc0..31,sum][lane] = 33 KB

  const int bid  = blockIdx.x;
  const int half = bid & 1;
  const int bh   = bid >> 1;
  const int b    = bh >> 6;
  const int h    = bh & 63;
  const int xw   = threadIdx.x & 63;
  const int wv   = __builtin_amdgcn_readfirstlane((int)(threadIdx.x >> 6));
  const int hh   = wv & 3;                 // head slot within block
  const int m    = half * 4 + hh;          // global head
  const int kh   = wv >> 2;                // k-half 0/1

  const float* kb = keyp + (size_t)b * CKEY * HWP + (h + 1) * ROWP + (xw + 1);
  const float* mb = mem + m * (CPH * HOUT);

  float acc[HOUT];
#pragma unroll
  for (int i = 0; i < HOUT; ++i) acc[i] = 0.0f;
  float sum = 0.0f;

  const int t0 = kh * (CPH / 2);
  for (int tg = t0; tg < t0 + CPH / 2; tg += 8) {
    float v[8];
#pragma unroll
    for (int k = 0; k < 8; ++k) {
      const int u   = 8 * (tg + k) + m;    // uniform SALU
      const int cch = u / 9;
      const int p   = u - 9 * cch;
      const int dy  = p / 3 - 1;
      const int dx  = p % 3 - 1;
      v[k] = kb[cch * HWP + dy * ROWP + dx];   // 8 gathers in flight
    }
#pragma unroll
    for (int k = 0; k < 8; ++k) {
      const float wt = __expf(v[k]);
      sum += wt;
      const float* mr = mb + (tg + k) * HOUT;  // uniform -> s_load rows
#pragma unroll
      for (int i = 0; i < HOUT; ++i)
        acc[i] = fmaf(wt, mr[i], acc[i]);
    }
  }

  if (kh == 1) {                           // wave-uniform branch
#pragma unroll
    for (int i = 0; i < HOUT; ++i) red[(hh * 33 + i) * 64 + xw] = acc[i];
    red[(hh * 33 + 32) * 64 + xw] = sum;
  }
  __syncthreads();
  if (kh == 0) {
#pragma unroll
    for (int i = 0; i < HOUT; ++i) acc[i] += red[(hh * 33 + i) * 64 + xw];
    sum += red[(hh * 33 + 32) * 64 + xw];
    const float inv = 1.0f / sum;
    float* ob = out + ((size_t)(b * NH + m) * HOUT) * HW + h * W_ + xw;
#pragma unroll
    for (int i = 0; i < HOUT; ++i)
      ob[(size_t)i * HW] = acc[i] * inv;   // coalesced
  }
}

extern "C" void kernel_launch(void* const* d_in, const int* in_sizes, int n_in,
                              void* d_out, int out_size, void* d_ws, size_t ws_size,
                              hipStream_t stream) {
  const float* x   = (const float*)d_in[0];
  const float* wk  = (const float*)d_in[1];
  const float* bk  = (const float*)d_in[2];
  const float* mem = (const float*)d_in[3];

  float* keyp = (float*)d_ws;                       // 35.68 MB padded scratch
  float* wT   = (float*)d_ws + (size_t)B_ * CKEY * HWP;  // +128 KB

  wtrans_kernel<<<dim3(CIN), dim3(CKEY), 0, stream>>>(wk, wT);
  border_zero_kernel<<<dim3(B_ * CKEY), dim3(320), 0, stream>>>(keyp);
  conv1x1_v3<<<dim3(B_ * 256), dim3(256), 0, stream>>>(x, wT, bk, keyp);
  attn_out_v3<<<dim3(B_ * 64 * 2), dim3(512), 0, stream>>>(keyp, mem, (float*)d_out);
}

// Round 4
// 155.465 us; speedup vs baseline: 2.3060x; 1.4220x over previous
//
#include <hip/hip_runtime.h>

// Problem constants
#define B_   8
#define CIN  128
#define CKEY 256   // N_HEADS*HEAD_DIM key channels
#define NH   8
#define HOUT 32    // OUT_CH / N_HEADS
#define CPH  288   // softmax length per head (2304/8)
#define HW   4096
#define ROWP 66    // padded row length (bf16 keyp)
#define HWP  4356  // 66*66 padded plane

typedef __attribute__((ext_vector_type(8))) short bf16x8;
typedef __attribute__((ext_vector_type(4))) float f32x4;

__device__ __forceinline__ unsigned short f2bf(float f) {  // RNE f32->bf16
  unsigned u = __builtin_bit_cast(unsigned, f);
  u += 0x7FFFu + ((u >> 16) & 1u);
  return (unsigned short)(u >> 16);
}
__device__ __forceinline__ float bf2f(unsigned short s) {
  return __builtin_bit_cast(float, ((unsigned)s) << 16);
}

// ---------------------------------------------------------------------------
// Prep A: pack W[och][ic] fp32 -> bf16 MFMA A-fragments.
// Layout: wfrag[(otg*4 + ks)*64 + lane][8], och = otg*16 + (lane&15),
// ic = ks*32 + (lane>>4)*8 + j.  (A[m][k]: m=lane&15, k=quad*8+j — verified)
// ---------------------------------------------------------------------------
__global__ __launch_bounds__(256) void wfrag_prep(
    const float* __restrict__ wk, unsigned short* __restrict__ wfrag)
{
  const int idx  = blockIdx.x * 256 + threadIdx.x;   // 0..4095
  const int lane = idx & 63, rest = idx >> 6;
  const int ks = rest & 3, otg = rest >> 2;
  const int li = lane & 15, q = lane >> 4;
  const int och = otg * 16 + li;
  const int ic0 = ks * 32 + q * 8;
  unsigned short* dst = wfrag + (size_t)idx * 8;
#pragma unroll
  for (int j = 0; j < 8; ++j) dst[j] = f2bf(wk[och * CIN + ic0 + j]);
}

// ---------------------------------------------------------------------------
// Prep B: pack memory[m][t][i] fp32 -> bf16 MFMA B-fragments.
// Layout: mfrag[((m*9 + c)*2 + ib)*64 + lane][8], t = c*32 + (lane>>4)*8 + j,
// i = ib*16 + (lane&15).  (B[k][n]: n=lane&15, k=quad*8+j)
// ---------------------------------------------------------------------------
__global__ __launch_bounds__(256) void mfrag_prep(
    const float* __restrict__ mem, unsigned short* __restrict__ mfrag)
{
  const int idx  = blockIdx.x * 256 + threadIdx.x;   // 0..9215
  const int lane = idx & 63, rest = idx >> 6;        // 0..143
  const int ib = rest & 1, mc = rest >> 1;           // 0..71
  const int c = mc % 9, m = mc / 9;
  const int li = lane & 15, q = lane >> 4;
  const int i  = ib * 16 + li;
  const int t0 = c * 32 + q * 8;
  unsigned short* dst = mfrag + (size_t)idx * 8;
#pragma unroll
  for (int j = 0; j < 8; ++j) dst[j] = f2bf(mem[(m * CPH + t0 + j) * HOUT + i]);
}

// ---------------------------------------------------------------------------
// Zero the 1-px border of each padded bf16 key plane.
// ---------------------------------------------------------------------------
__global__ __launch_bounds__(320) void border_zero(unsigned short* __restrict__ keyp)
{
  const int plane = blockIdx.x;            // b*256 + c
  const int e = threadIdx.x;
  if (e >= 260) return;
  int r, cc;
  if (e < 66)       { r = 0;       cc = e; }
  else if (e < 132) { r = 65;      cc = e - 66; }
  else if (e < 196) { r = e - 131; cc = 0; }
  else              { r = e - 195; cc = 65; }
  keyp[(size_t)plane * HWP + r * ROWP + cc] = 0;
}

// ---------------------------------------------------------------------------
// Conv 1x1 via MFMA: C[och][px] = W[och][ic] * x[ic][px] + bias.
// grid = (b,h) = 512 blocks x 512 thr = 8 waves: wave = (oq 0..3, xh 0..1).
// Per wave: 4 och-tiles x 2 px-tiles, K = 128 = 4 steps of 32.
// A from wfrag (dwordx4), B from x fp32 (coalesced: 16 consecutive px per
// quad-row) converted to bf16 in-register. Bias folded into C-init.
// C layout: row = och-off = 4q+r, col = px-off = lane&15 (verified).
// Output: keyp bf16 padded [b][och][66][66] interior.
// ---------------------------------------------------------------------------
__global__ __launch_bounds__(512, 4) void conv_mfma(
    const float* __restrict__ x, const unsigned short* __restrict__ wfrag,
    const float* __restrict__ bk, unsigned short* __restrict__ keyp)
{
  const int tid  = threadIdx.x;
  const int lane = tid & 63, wv = tid >> 6;
  const int li = lane & 15, q = lane >> 4;
  const int oq = wv >> 1, xh = wv & 1;
  const int bid = blockIdx.x;
  const int b = bid >> 6, h = bid & 63;

  f32x4 c[4][2];
#pragma unroll
  for (int ot = 0; ot < 4; ++ot) {
    const float4 bv = *(const float4*)(bk + oq * 64 + ot * 16 + 4 * q);
    f32x4 cv; cv[0] = bv.x; cv[1] = bv.y; cv[2] = bv.z; cv[3] = bv.w;
    c[ot][0] = cv; c[ot][1] = cv;
  }

  const float* xb = x + (size_t)b * CIN * HW + h * 64 + xh * 32 + li;

#pragma unroll
  for (int ks = 0; ks < 4; ++ks) {
    bf16x8 bf[2];
#pragma unroll
    for (int pt = 0; pt < 2; ++pt) {
      unsigned pk[4];
#pragma unroll
      for (int j = 0; j < 8; ++j) {
        const int ic = ks * 32 + q * 8 + j;
        const float xv = xb[(size_t)ic * HW + pt * 16];
        const unsigned short s = f2bf(xv);
        if (j & 1) pk[j >> 1] |= ((unsigned)s) << 16; else pk[j >> 1] = s;
      }
      const int4 t = make_int4(pk[0], pk[1], pk[2], pk[3]);
      bf[pt] = __builtin_bit_cast(bf16x8, t);
    }
#pragma unroll
    for (int ot = 0; ot < 4; ++ot) {
      const bf16x8 af = *(const bf16x8*)(
          wfrag + ((size_t)((oq * 4 + ot) * 4 + ks) * 64 + lane) * 8);
      c[ot][0] = __builtin_amdgcn_mfma_f32_16x16x32_bf16(af, bf[0], c[ot][0], 0, 0, 0);
      c[ot][1] = __builtin_amdgcn_mfma_f32_16x16x32_bf16(af, bf[1], c[ot][1], 0, 0, 0);
    }
  }

#pragma unroll
  for (int ot = 0; ot < 4; ++ot)
#pragma unroll
    for (int pt = 0; pt < 2; ++pt)
#pragma unroll
      for (int r = 0; r < 4; ++r) {
        const int och = oq * 64 + ot * 16 + 4 * q + r;
        const int px  = xh * 32 + pt * 16 + li;
        keyp[(size_t)(b * CKEY + och) * HWP + (h + 1) * ROWP + 1 + px] =
            f2bf(c[ot][pt][r]);
      }
}

// ---------------------------------------------------------------------------
// Attention + memory matvec via MFMA.
// grid = (b,h,ph) = 1024 blocks x 512 thr = 8 waves = 8 heads; wave covers
// px = ph*32 + [0,32) as 2 pxblk of 16, all 288 t as 9 K-chunks of 32.
// P generated DIRECTLY in A-fragment layout: lane (li,q) computes
// wt(px0+li, t = 32c+8q+j) for j=0..7 -> no LDS transpose, no redundancy.
// u = 8t+m, cch=u/9, p=u%9; elem = cch*HWP + (h + p/3)*66 + (p%3) + px
// (zero bf16 border already materialized). Softmax denom kept fp32 per-lane,
// reduced with 2 shfl_xor, applied in epilogue. M from prepacked B-frags.
// C layout: row = px-off = 4q+r, col = i-off = li. Small per-wave LDS tile
// transposes C so global stores are px-contiguous.
// ---------------------------------------------------------------------------
__global__ __launch_bounds__(512, 4) void attn_mfma(
    const unsigned short* __restrict__ keyp,
    const unsigned short* __restrict__ mfrag, float* __restrict__ out)
{
  __shared__ float tile[NH][16][33];       // per-wave transpose scratch, 16.5 KB

  const int tid  = threadIdx.x;
  const int lane = tid & 63;
  const int m    = tid >> 6;               // head = wave
  const int li = lane & 15, q = lane >> 4;
  const int bid = blockIdx.x;
  const int ph = bid & 1, h = (bid >> 1) & 63, b = bid >> 7;

  const size_t kbase = (size_t)b * CKEY * HWP;
  const unsigned short* mf = mfrag + (size_t)m * 9 * 2 * 64 * 8;
  float* ob = out + ((size_t)b * CKEY + m * HOUT) * HW + h * 64 + ph * 32;

#pragma unroll
  for (int pb = 0; pb < 2; ++pb) {
    const int px = ph * 32 + pb * 16 + li;
    f32x4 c0 = {0.f, 0.f, 0.f, 0.f};
    f32x4 c1 = {0.f, 0.f, 0.f, 0.f};
    float ssum = 0.f;

    for (int c = 0; c < 9; ++c) {
      unsigned pk[4];
#pragma unroll
      for (int j = 0; j < 8; ++j) {
        const int t   = c * 32 + q * 8 + j;    // this lane's k-index
        const int u   = t * 8 + m;
        const int cch = u / 9;                 // magic-mul
        const int p   = u - cch * 9;
        const int fp  = (p * 11) >> 5;         // p/3
        const size_t elem = kbase + (size_t)cch * HWP
                          + (h + fp) * ROWP + (p - 3 * fp) + px;
        const float v  = bf2f(keyp[elem]);
        const float w  = __expf(v);            // shift-free softmax (R2-safe)
        ssum += w;
        const unsigned short s = f2bf(w);
        if (j & 1) pk[j >> 1] |= ((unsigned)s) << 16; else pk[j >> 1] = s;
      }
      const int4 ti = make_int4(pk[0], pk[1], pk[2], pk[3]);
      const bf16x8 af = __builtin_bit_cast(bf16x8, ti);

      const bf16x8 b0 = *(const bf16x8*)(mf + ((size_t)(c * 2 + 0) * 64 + lane) * 8);
      const bf16x8 b1 = *(const bf16x8*)(mf + ((size_t)(c * 2 + 1) * 64 + lane) * 8);
      c0 = __builtin_amdgcn_mfma_f32_16x16x32_bf16(af, b0, c0, 0, 0, 0);
      c1 = __builtin_amdgcn_mfma_f32_16x16x32_bf16(af, b1, c1, 0, 0, 0);
    }

    // full softmax denominator for this lane's px (= li-indexed after reduce)
    ssum += __shfl_xor(ssum, 16, 64);
    ssum += __shfl_xor(ssum, 32, 64);
    const float inv = 1.0f / ssum;

    // scale rows by their px's inv-sum and transpose via LDS
#pragma unroll
    for (int r = 0; r < 4; ++r) {
      const float invr = __shfl(inv, q * 4 + r, 64);  // inv for row-px 4q+r
      tile[m][q * 4 + r][li]      = c0[r] * invr;
      tile[m][q * 4 + r][16 + li] = c1[r] * invr;
    }
    // same-wave RAW through LDS: compiler orders ds ops + lgkmcnt (no barrier:
    // each wave owns tile[m])
#pragma unroll
    for (int s = 0; s < 8; ++s) {
      const int i = s * 4 + q;
      const float val = tile[m][li][i];
      ob[(size_t)i * HW + pb * 16 + li] = val;   // 4 x 64B segments per store
    }
  }
}

extern "C" void kernel_launch(void* const* d_in, const int* in_sizes, int n_in,
                              void* d_out, int out_size, void* d_ws, size_t ws_size,
                              hipStream_t stream) {
  const float* x   = (const float*)d_in[0];
  const float* wk  = (const float*)d_in[1];
  const float* bk  = (const float*)d_in[2];
  const float* mem = (const float*)d_in[3];

  unsigned short* keyp  = (unsigned short*)d_ws;                 // 17,842,176 B
  unsigned short* wfrag = (unsigned short*)((char*)d_ws + 17842176);   // 65,536 B
  unsigned short* mfrag = (unsigned short*)((char*)d_ws + 17907712);   // 147,456 B

  wfrag_prep <<<dim3(16),        dim3(256), 0, stream>>>(wk, wfrag);
  mfrag_prep <<<dim3(36),        dim3(256), 0, stream>>>(mem, mfrag);
  border_zero<<<dim3(B_ * CKEY), dim3(320), 0, stream>>>(keyp);
  conv_mfma  <<<dim3(B_ * 64),   dim3(512), 0, stream>>>(x, wfrag, bk, keyp);
  attn_mfma  <<<dim3(B_ * 64 * 2), dim3(512), 0, stream>>>(keyp, mfrag, (float*)d_out);
}

// Round 5
// 146.739 us; speedup vs baseline: 2.4431x; 1.0595x over previous
//
#include <hip/hip_runtime.h>

// Problem constants
#define B_   8
#define CIN  128
#define CKEY 256   // N_HEADS*HEAD_DIM key channels
#define NH   8
#define HOUT 32    // OUT_CH / N_HEADS
#define CPH  288   // softmax length per head (2304/8)
#define HW   4096
#define ROWP 66    // padded row length (bf16 keyp)
#define HWP  4356  // 66*66 padded plane

typedef __attribute__((ext_vector_type(8))) short bf16x8;
typedef __attribute__((ext_vector_type(4))) float f32x4;

__device__ __forceinline__ unsigned short f2bf(float f) {  // RNE f32->bf16
  unsigned u = __builtin_bit_cast(unsigned, f);
  u += 0x7FFFu + ((u >> 16) & 1u);
  return (unsigned short)(u >> 16);
}

// ---------------------------------------------------------------------------
// Prep A: pack W[och][ic] fp32 -> bf16 MFMA A-fragments.
// wfrag[(otg*4 + ks)*64 + lane][8]: och = otg*16 + (lane&15), ic = ks*32+q*8+j
// ---------------------------------------------------------------------------
__global__ __launch_bounds__(256) void wfrag_prep(
    const float* __restrict__ wk, unsigned short* __restrict__ wfrag)
{
  const int idx  = blockIdx.x * 256 + threadIdx.x;   // 0..4095
  const int lane = idx & 63, rest = idx >> 6;
  const int ks = rest & 3, otg = rest >> 2;
  const int li = lane & 15, q = lane >> 4;
  const int och = otg * 16 + li;
  const int ic0 = ks * 32 + q * 8;
  unsigned short* dst = wfrag + (size_t)idx * 8;
#pragma unroll
  for (int j = 0; j < 8; ++j) dst[j] = f2bf(wk[och * CIN + ic0 + j]);
}

// ---------------------------------------------------------------------------
// Prep B: pack memory[m][t][i] fp32 -> bf16 MFMA B-fragments.
// mfrag[((m*9+c)*2+ib)*64 + lane][8]: t = c*32+q*8+j, i = ib*16 + (lane&15)
// ---------------------------------------------------------------------------
__global__ __launch_bounds__(256) void mfrag_prep(
    const float* __restrict__ mem, unsigned short* __restrict__ mfrag)
{
  const int idx  = blockIdx.x * 256 + threadIdx.x;   // 0..9215
  const int lane = idx & 63, rest = idx >> 6;        // 0..143
  const int ib = rest & 1, mc = rest >> 1;           // 0..71
  const int c = mc % 9, m = mc / 9;
  const int li = lane & 15, q = lane >> 4;
  const int i  = ib * 16 + li;
  const int t0 = c * 32 + q * 8;
  unsigned short* dst = mfrag + (size_t)idx * 8;
#pragma unroll
  for (int j = 0; j < 8; ++j) dst[j] = f2bf(mem[(m * CPH + t0 + j) * HOUT + i]);
}

// ---------------------------------------------------------------------------
// Zero the 1-px border of each padded bf16 key plane. XCD-swizzled (b=bid&7).
// ---------------------------------------------------------------------------
__global__ __launch_bounds__(320) void border_zero(unsigned short* __restrict__ keyp)
{
  const int b = blockIdx.x & 7, c = blockIdx.x >> 3;
  const int plane = b * CKEY + c;
  const int e = threadIdx.x;
  if (e >= 260) return;
  int r, cc;
  if (e < 66)       { r = 0;       cc = e; }
  else if (e < 132) { r = 65;      cc = e - 66; }
  else if (e < 196) { r = e - 131; cc = 0; }
  else              { r = e - 195; cc = 65; }
  keyp[(size_t)plane * HWP + r * ROWP + cc] = 0;
}

// ---------------------------------------------------------------------------
// Conv 1x1 via MFMA, LDS-staged x.
// grid = 512 (b = bid&7 XCD-swizzle, h = bid>>3); 512 thr = 8 waves (oq,xh).
// Stage x[b,:,h,:] (128ic x 64px fp32) into xT[px][132] via coalesced dword
// loads + ds_write_b128 (conflict-free: 8-lane phases hit distinct banks).
// Fragments: ds_read_b128 x2 (conflict-free), RNE-convert to bf16 at use.
// ---------------------------------------------------------------------------
__global__ __launch_bounds__(512, 4) void conv_mfma(
    const float* __restrict__ x, const unsigned short* __restrict__ wfrag,
    const float* __restrict__ bk, unsigned short* __restrict__ keyp)
{
  __shared__ float xT[64][132];            // 33792 B; stride 132: b128-aligned

  const int t   = threadIdx.x;
  const int bid = blockIdx.x;
  const int b = bid & 7, h = bid >> 3;

  // ---- stage: thread (px = t&63, icg = t>>6) loads 4 rounds of 4 ic's
  {
    const int px  = t & 63;
    const int icg = t >> 6;                // 0..7
    const float* xb = x + (size_t)b * CIN * HW + h * 64 + px;
#pragma unroll
    for (int r = 0; r < 4; ++r) {
      const int ic4 = 4 * icg + 32 * r;
      float4 v;
      v.x = xb[(size_t)(ic4 + 0) * HW];    // each: 64 consecutive px, coalesced
      v.y = xb[(size_t)(ic4 + 1) * HW];
      v.z = xb[(size_t)(ic4 + 2) * HW];
      v.w = xb[(size_t)(ic4 + 3) * HW];
      *(float4*)&xT[px][ic4] = v;          // b128, 8-lane phases conflict-free
    }
  }
  __syncthreads();

  const int lane = t & 63, wv = t >> 6;
  const int li = lane & 15, q = lane >> 4;
  const int oq = wv >> 1, xh = wv & 1;

  f32x4 c[4][2];
#pragma unroll
  for (int ot = 0; ot < 4; ++ot) {
    const float4 bv = *(const float4*)(bk + oq * 64 + ot * 16 + 4 * q);
    f32x4 cv; cv[0] = bv.x; cv[1] = bv.y; cv[2] = bv.z; cv[3] = bv.w;
    c[ot][0] = cv; c[ot][1] = cv;
  }

#pragma unroll
  for (int ks = 0; ks < 4; ++ks) {
    bf16x8 bf[2];
#pragma unroll
    for (int pt = 0; pt < 2; ++pt) {
      const int pxx = xh * 32 + pt * 16 + li;
      const float4 a0 = *(const float4*)&xT[pxx][ks * 32 + q * 8];
      const float4 a1 = *(const float4*)&xT[pxx][ks * 32 + q * 8 + 4];
      const float vals[8] = {a0.x, a0.y, a0.z, a0.w, a1.x, a1.y, a1.z, a1.w};
      unsigned pk[4];
#pragma unroll
      for (int j = 0; j < 8; ++j) {
        const unsigned short s = f2bf(vals[j]);
        if (j & 1) pk[j >> 1] |= ((unsigned)s) << 16; else pk[j >> 1] = s;
      }
      const int4 ti = make_int4(pk[0], pk[1], pk[2], pk[3]);
      bf[pt] = __builtin_bit_cast(bf16x8, ti);
    }
#pragma unroll
    for (int ot = 0; ot < 4; ++ot) {
      const bf16x8 af = *(const bf16x8*)(
          wfrag + ((size_t)((oq * 4 + ot) * 4 + ks) * 64 + lane) * 8);
      c[ot][0] = __builtin_amdgcn_mfma_f32_16x16x32_bf16(af, bf[0], c[ot][0], 0, 0, 0);
      c[ot][1] = __builtin_amdgcn_mfma_f32_16x16x32_bf16(af, bf[1], c[ot][1], 0, 0, 0);
    }
  }

#pragma unroll
  for (int ot = 0; ot < 4; ++ot)
#pragma unroll
    for (int pt = 0; pt < 2; ++pt)
#pragma unroll
      for (int r = 0; r < 4; ++r) {
        const int och = oq * 64 + ot * 16 + 4 * q + r;
        const int px  = xh * 32 + pt * 16 + li;
        keyp[(size_t)(b * CKEY + och) * HWP + (h + 1) * ROWP + 1 + px] =
            f2bf(c[ot][pt][r]);
      }
}

// ---------------------------------------------------------------------------
// Attention + memory matvec via MFMA, LDS offset table.
// grid = 1024 (b = bid&7 XCD-swizzle -> keyp L2-local; rest = (h,ph)).
// off[u] table (u = 8t+m): per-element gather addr = table + (h,px) base --
// no integer mults in the hot loop. Slot skew (u>>6)*65+(u&63) makes the
// 4 quad-broadcast reads hit distinct banks. wt packed by TRUNCATION; the
// denominator sums the same truncated values so the rounding bias cancels.
// mfrag B-frags hoisted: loaded once per c-chunk, shared by both px-halves.
// ---------------------------------------------------------------------------
__global__ __launch_bounds__(512, 4) void attn_mfma(
    const unsigned short* __restrict__ keyp,
    const unsigned short* __restrict__ mfrag, float* __restrict__ out)
{
  __shared__ float tile[NH][16][33];       // 16896 B epilogue transpose
  __shared__ int offs[36 * 65];            // 9360 B skewed offset table

  const int t   = threadIdx.x;
  const int bid = blockIdx.x;
  const int b    = bid & 7;
  const int rest = bid >> 3;
  const int ph = rest & 1, h = rest >> 1;

  // ---- build off[u] = byte offset of logit u within batch-b keyp (px part excl.)
  for (int e = t; e < 2304; e += 512) {
    const int u   = e;
    const int cch = u / 9;
    const int p   = u - 9 * cch;
    const int fp  = (p * 11) >> 5;         // p/3
    offs[(u >> 6) * 65 + (u & 63)] = (cch * HWP + fp * ROWP + (p - 3 * fp)) * 2;
  }
  __syncthreads();

  const int lane = t & 63;
  const int m    = t >> 6;                 // head = wave
  const int li = lane & 15, q = lane >> 4;

  const char* kb = (const char*)keyp + (size_t)b * CKEY * HWP * 2;
  const unsigned short* mf = mfrag + (size_t)m * 9 * 2 * 64 * 8;

  const int vq  = 65 * q + m;                        // dword idx into offs
  const int hb0 = (h * ROWP + ph * 32 + li) * 2;     // byte base, pb=0 (+32 for pb=1)

  f32x4 acc[2][2];
#pragma unroll
  for (int pb = 0; pb < 2; ++pb) { acc[pb][0] = {0,0,0,0}; acc[pb][1] = {0,0,0,0}; }
  float ssum[2] = {0.f, 0.f};

  for (int c = 0; c < 9; ++c) {
    int o[8];
#pragma unroll
    for (int j = 0; j < 8; ++j)
      o[j] = offs[vq + 260 * c + 8 * j];   // quad-broadcast, distinct banks

    const bf16x8 b0 = *(const bf16x8*)(mf + ((size_t)(c * 2 + 0) * 64 + lane) * 8);
    const bf16x8 b1 = *(const bf16x8*)(mf + ((size_t)(c * 2 + 1) * 64 + lane) * 8);

    unsigned pk[2][4];
#pragma unroll
    for (int pb = 0; pb < 2; ++pb) {
      const int hb = hb0 + pb * 32;
#pragma unroll
      for (int j = 0; j < 8; ++j) {
        const unsigned short sv = *(const unsigned short*)(kb + (unsigned)(o[j] + hb));
        const float v = __builtin_bit_cast(float, ((unsigned)sv) << 16);
        const float w = __expf(v);         // shift-free softmax
        const unsigned uw = __builtin_bit_cast(unsigned, w) & 0xFFFF0000u;
        ssum[pb] += __builtin_bit_cast(float, uw);   // sum SAME truncation
        if (j & 1) pk[pb][j >> 1] |= uw;             // odd j -> high half
        else       pk[pb][j >> 1] = uw >> 16;        // even j -> low half
      }
    }
#pragma unroll
    for (int pb = 0; pb < 2; ++pb) {
      const int4 ti = make_int4(pk[pb][0], pk[pb][1], pk[pb][2], pk[pb][3]);
      const bf16x8 af = __builtin_bit_cast(bf16x8, ti);
      acc[pb][0] = __builtin_amdgcn_mfma_f32_16x16x32_bf16(af, b0, acc[pb][0], 0, 0, 0);
      acc[pb][1] = __builtin_amdgcn_mfma_f32_16x16x32_bf16(af, b1, acc[pb][1], 0, 0, 0);
    }
  }

  float* ob = out + ((size_t)b * CKEY + m * HOUT) * HW + h * 64 + ph * 32;
#pragma unroll
  for (int pb = 0; pb < 2; ++pb) {
    float s = ssum[pb];
    s += __shfl_xor(s, 16, 64);
    s += __shfl_xor(s, 32, 64);
    const float inv = 1.0f / s;
#pragma unroll
    for (int r = 0; r < 4; ++r) {
      const float invr = __shfl(inv, q * 4 + r, 64);   // inv of row-px 4q+r
      tile[m][q * 4 + r][li]      = acc[pb][0][r] * invr;
      tile[m][q * 4 + r][16 + li] = acc[pb][1][r] * invr;
    }
    // same-wave RAW through LDS (wave owns tile[m]); no barrier needed
#pragma unroll
    for (int s2 = 0; s2 < 8; ++s2) {
      const int i = s2 * 4 + q;
      ob[(size_t)i * HW + pb * 16 + li] = tile[m][li][i];  // 64B segments
    }
  }
}

extern "C" void kernel_launch(void* const* d_in, const int* in_sizes, int n_in,
                              void* d_out, int out_size, void* d_ws, size_t ws_size,
                              hipStream_t stream) {
  const float* x   = (const float*)d_in[0];
  const float* wk  = (const float*)d_in[1];
  const float* bk  = (const float*)d_in[2];
  const float* mem = (const float*)d_in[3];

  unsigned short* keyp  = (unsigned short*)d_ws;                       // 17,842,176 B
  unsigned short* wfrag = (unsigned short*)((char*)d_ws + 17842176);   // 65,536 B
  unsigned short* mfrag = (unsigned short*)((char*)d_ws + 17907712);   // 147,456 B

  wfrag_prep <<<dim3(16),          dim3(256), 0, stream>>>(wk, wfrag);
  mfrag_prep <<<dim3(36),          dim3(256), 0, stream>>>(mem, mfrag);
  border_zero<<<dim3(B_ * CKEY),   dim3(320), 0, stream>>>(keyp);
  conv_mfma  <<<dim3(B_ * 64),     dim3(512), 0, stream>>>(x, wfrag, bk, keyp);
  attn_mfma  <<<dim3(B_ * 64 * 2), dim3(512), 0, stream>>>(keyp, mfrag, (float*)d_out);
}

// Round 6
// 101.641 us; speedup vs baseline: 3.5271x; 1.4437x over previous
//
#include <hip/hip_runtime.h>

// Problem constants
#define B_   8
#define CIN  128
#define CKEY 256   // N_HEADS*HEAD_DIM key channels
#define NH   8
#define HOUT 32    // OUT_CH / N_HEADS
#define CPH  288   // softmax length per head
#define HW   4096

// LDS geometry
#define XSTR   136                 // xT stride in bf16 (68 dwords, b128-aligned, swizzled)
#define ESTR   264                 // E2 x-stride in bf16 (132 dwords; li*4 banks = 2-way free)
#define EROW   (66 * ESTR)         // 17424 elems per y-row
#define E2_BYTES   (3 * EROW * 2)            // 104544
#define XBUF_BYTES (64 * XSTR * 2)           // 17408
#define SMEM_BYTES (E2_BYTES + 2 * XBUF_BYTES)  // 139360 <= 160 KiB

typedef __attribute__((ext_vector_type(8))) short bf16x8;
typedef __attribute__((ext_vector_type(4))) float f32x4;

__device__ __forceinline__ unsigned short f2bf(float f) {  // RNE f32->bf16
  unsigned u = __builtin_bit_cast(unsigned, f);
  u += 0x7FFFu + ((u >> 16) & 1u);
  return (unsigned short)(u >> 16);
}

// ---------------------------------------------------------------------------
// Prep A: W[och][ic] -> bf16 A-frags in PERMUTED och order: tile (cm,sh) has
// m-idx li -> och = cm + 8*(sh*16+li); k = q*8+j -> ic = ks*32+q*8+j.
// fragid fi = (cm*2+sh)*4+ks, 64 frags x 64 lanes x 8.
// ---------------------------------------------------------------------------
__global__ __launch_bounds__(256) void wfragP_prep(
    const float* __restrict__ wk, unsigned short* __restrict__ wfragP)
{
  const int idx  = blockIdx.x * 256 + threadIdx.x;   // 0..4095
  const int lane = idx & 63, fi = idx >> 6;
  const int ks = fi & 3, sh = (fi >> 2) & 1, cm = fi >> 3;
  const int li = lane & 15, q = lane >> 4;
  const int och = cm + 8 * (sh * 16 + li);
  const int ic0 = ks * 32 + q * 8;
  unsigned short* dst = wfragP + (size_t)idx * 8;
#pragma unroll
  for (int j = 0; j < 8; ++j) dst[j] = f2bf(wk[och * CIN + ic0 + j]);
}

// ---------------------------------------------------------------------------
// Prep B: memory[m][t][i] -> bf16 B-frags reindexed by (m,p,s):
// c = ((m-p)&7) + 8s, t = (9c+p)>>3.  n = li -> i = ib*16+li, k = q*8+j -> s.
// fragid fi = (m*9+p)*2+ib, 144 frags.
// ---------------------------------------------------------------------------
__global__ __launch_bounds__(256) void mfragP_prep(
    const float* __restrict__ mem, unsigned short* __restrict__ mfragP)
{
  const int idx  = blockIdx.x * 256 + threadIdx.x;   // 0..9215
  const int lane = idx & 63, fi = idx >> 6;          // 0..143
  const int ib = fi & 1, pm = fi >> 1;
  const int p = pm % 9, m = pm / 9;
  const int li = lane & 15, q = lane >> 4;
  const int i  = ib * 16 + li;
  unsigned short* dst = mfragP + (size_t)idx * 8;
#pragma unroll
  for (int j = 0; j < 8; ++j) {
    const int s = q * 8 + j;
    const int c = ((m - p + 8) & 7) + 8 * s;
    const int t = (9 * c + p) >> 3;
    dst[j] = f2bf(mem[(m * CPH + t) * HOUT + i]);
  }
}

// ---------------------------------------------------------------------------
// Fused conv + softmax + matvec. grid = 512 (b = bid&7, h = bid>>3), 512 thr
// = 8 waves. Phases:
//  1) stage x rows h-1..h+1 (bf16, swizzled xT in LDS, double-buffered)
//  2) conv via MFMA (wave = cm-class), epilogue exp -> E2[y][x][cm][s] bf16
//     (borders = 1.0 = exp(0): zero-pad logits participate in softmax)
//  3) attn: wave = head m; per (p,pb): ONE ds_read_b128 A-frag; 3 MFMA
//     (2 out-cols + 1 ones-B for the softmax denominator, row-aligned)
//  4) epilogue: scale by 1/denominator, LDS transpose (reuses xbuf), wide store
// ---------------------------------------------------------------------------
__global__ __launch_bounds__(512, 2) void fused_kernel(
    const float* __restrict__ x, const unsigned short* __restrict__ wfragP,
    const unsigned short* __restrict__ mfragP, const float* __restrict__ bk,
    float* __restrict__ out)
{
  extern __shared__ char smem[];
  unsigned short* e2  = (unsigned short*)smem;
  unsigned short* xb0 = (unsigned short*)(smem + E2_BYTES);
  unsigned short* xb1 = xb0 + 64 * XSTR;
  float* tileb = (float*)(smem + E2_BYTES);   // epilogue reuse of xbuf region

  const int tid = threadIdx.x;
  const int bid = blockIdx.x;
  const int b = bid & 7, h = bid >> 3;        // XCD swizzle: batch per XCD
  const int lane = tid & 63;
  const int wv = __builtin_amdgcn_readfirstlane(tid >> 6);
  const int li = lane & 15, q = lane >> 4;

  // ---- bias, permuted: tile (cm=wv, sh), row r -> och = wv + 8*(sh*16+4q+r)
  float bias[2][4];
#pragma unroll
  for (int sh = 0; sh < 2; ++sh)
#pragma unroll
    for (int r = 0; r < 4; ++r)
      bias[sh][r] = bk[wv + 8 * (sh * 16 + 4 * q + r)];

  // ================= stage helpers =================
  const int spx = tid & 63, sicg = tid >> 6;
  const int sxor = ((spx >> 3) & 7) << 3;     // bank-swizzle (16B blocks)

  auto stage_load = [&](int y, unsigned* pk) {
    const float* xr = x + (size_t)b * CIN * HW + y * 64 + spx;
#pragma unroll
    for (int r4 = 0; r4 < 4; ++r4) {
      const int ic0 = 4 * sicg + 32 * r4;
      const float v0 = xr[(size_t)(ic0 + 0) * HW];  // 256B coalesced each
      const float v1 = xr[(size_t)(ic0 + 1) * HW];
      const float v2 = xr[(size_t)(ic0 + 2) * HW];
      const float v3 = xr[(size_t)(ic0 + 3) * HW];
      pk[2 * r4 + 0] = (unsigned)f2bf(v0) | ((unsigned)f2bf(v1) << 16);
      pk[2 * r4 + 1] = (unsigned)f2bf(v2) | ((unsigned)f2bf(v3) << 16);
    }
  };
  auto stage_write = [&](unsigned short* xb, const unsigned* pk) {
    unsigned* xdw = (unsigned*)xb;
#pragma unroll
    for (int r4 = 0; r4 < 4; ++r4) {
      const int o = (2 * sicg + 16 * r4) ^ sxor;
      *(uint2*)(xdw + spx * 68 + o) = make_uint2(pk[2 * r4], pk[2 * r4 + 1]);
    }
  };

  // ================= conv one row into E2[rrow] =================
  auto conv_row = [&](const unsigned short* xb, int rrow) {
    f32x4 acc[2][4];                       // [sh][pt]
#pragma unroll
    for (int sh = 0; sh < 2; ++sh)
#pragma unroll
      for (int pt = 0; pt < 4; ++pt) {
        f32x4 cv; cv[0] = bias[sh][0]; cv[1] = bias[sh][1];
        cv[2] = bias[sh][2]; cv[3] = bias[sh][3];
        acc[sh][pt] = cv;
      }
    const unsigned* xdw = (const unsigned*)xb;
#pragma unroll
    for (int ks = 0; ks < 4; ++ks) {
      const bf16x8 a0 = *(const bf16x8*)(
          wfragP + ((size_t)(((wv * 2 + 0) * 4 + ks) * 64 + lane)) * 8);
      const bf16x8 a1 = *(const bf16x8*)(
          wfragP + ((size_t)(((wv * 2 + 1) * 4 + ks) * 64 + lane)) * 8);
#pragma unroll
      for (int pt = 0; pt < 4; ++pt) {
        const int px  = pt * 16 + li;
        const int blk = (ks * 16 + q * 4) ^ (((px >> 3) & 7) << 3);
        const bf16x8 bfr = *(const bf16x8*)(xdw + px * 68 + blk);
        acc[0][pt] = __builtin_amdgcn_mfma_f32_16x16x32_bf16(a0, bfr, acc[0][pt], 0, 0, 0);
        acc[1][pt] = __builtin_amdgcn_mfma_f32_16x16x32_bf16(a1, bfr, acc[1][pt], 0, 0, 0);
      }
    }
    // exp + write: lane's 4 rows = s = sh*16+4q+r (contiguous) -> ds_write_b64
    unsigned short* erow = e2 + rrow * EROW;
#pragma unroll
    for (int sh = 0; sh < 2; ++sh)
#pragma unroll
      for (int pt = 0; pt < 4; ++pt) {
        const float w0 = __expf(acc[sh][pt][0]);
        const float w1 = __expf(acc[sh][pt][1]);
        const float w2 = __expf(acc[sh][pt][2]);
        const float w3 = __expf(acc[sh][pt][3]);
        const unsigned d0 = (unsigned)f2bf(w0) | ((unsigned)f2bf(w1) << 16);
        const unsigned d1 = (unsigned)f2bf(w2) | ((unsigned)f2bf(w3) << 16);
        unsigned short* dst = erow + (pt * 16 + li + 1) * ESTR
                            + wv * 32 + sh * 16 + 4 * q;
        *(uint2*)dst = make_uint2(d0, d1);
      }
    // x-borders (x=0,65) = exp(0) = 1.0
    if (tid < 256) {
      const int xcol = (tid & 1) ? 65 : 0;
      ((unsigned*)(erow + xcol * ESTR))[tid >> 1] = 0x3F803F80u;
    }
  };
  auto fill_row = [&](int rrow) {           // whole y-row out of range -> 1.0
    unsigned* erow = (unsigned*)(e2 + rrow * EROW);
    for (int d = tid; d < 66 * 132; d += 512) erow[d] = 0x3F803F80u;
  };

  // ================= phase 1+2: build E2 =================
  const bool v0r = (h - 1 >= 0), v2r = (h + 1 < 64);
  unsigned pk0[8], pk1[8], pk2[8];
  if (v0r) stage_load(h - 1, pk0);
  stage_load(h, pk1);
  if (v2r) stage_load(h + 1, pk2);
  if (v0r) stage_write(xb0, pk0);
  stage_write(xb1, pk1);
  __syncthreads();                          // xb0,xb1 ready
  if (v0r) conv_row(xb0, 0); else fill_row(0);
  __syncthreads();                          // conv0's xb0 reads done
  if (v2r) stage_write(xb0, pk2);
  __syncthreads();                          // xb0 = row h+1
  conv_row(xb1, 1);
  if (v2r) conv_row(xb0, 2); else fill_row(2);
  __syncthreads();                          // E2 complete

  // ================= phase 3: attention =================
  const int m = wv;                         // wave = head
  const unsigned short* mf = mfragP + (size_t)(m * 9) * 2 * 64 * 8;
  const int4 onesi = make_int4(0x3F803F80, 0x3F803F80, 0x3F803F80, 0x3F803F80);
  const bf16x8 bones = __builtin_bit_cast(bf16x8, onesi);

  f32x4 acc[4][2], accs[4];
#pragma unroll
  for (int pb = 0; pb < 4; ++pb) {
    acc[pb][0] = {0.f, 0.f, 0.f, 0.f};
    acc[pb][1] = {0.f, 0.f, 0.f, 0.f};
    accs[pb]   = {0.f, 0.f, 0.f, 0.f};
  }

#pragma unroll
  for (int p = 0; p < 9; ++p) {
    const bf16x8 bm0 = *(const bf16x8*)(mf + ((size_t)((p * 2 + 0) * 64 + lane)) * 8);
    const bf16x8 bm1 = *(const bf16x8*)(mf + ((size_t)((p * 2 + 1) * 64 + lane)) * 8);
    const int cm   = (m - p + 8) & 7;
    const int rrow = p / 3;                 // dy+1
    const int dxp  = p - 3 * rrow;          // dx+1
    const unsigned short* abase = e2 + rrow * EROW + (li + dxp) * ESTR
                                + cm * 32 + q * 8;
#pragma unroll
    for (int pb = 0; pb < 4; ++pb) {
      const bf16x8 af = *(const bf16x8*)(abase + pb * 16 * ESTR);  // ds_read_b128
      acc[pb][0] = __builtin_amdgcn_mfma_f32_16x16x32_bf16(af, bm0, acc[pb][0], 0, 0, 0);
      acc[pb][1] = __builtin_amdgcn_mfma_f32_16x16x32_bf16(af, bm1, acc[pb][1], 0, 0, 0);
      accs[pb]   = __builtin_amdgcn_mfma_f32_16x16x32_bf16(af, bones, accs[pb], 0, 0, 0);
    }
  }

  // ================= phase 4: epilogue =================
  float* tw = tileb + wv * (16 * 33);       // per-wave transpose scratch
  float* ob = out + ((size_t)(b * CKEY + m * HOUT)) * HW + h * 64;
#pragma unroll
  for (int pb = 0; pb < 4; ++pb) {
#pragma unroll
    for (int r = 0; r < 4; ++r) {
      const float inv = 1.0f / accs[pb][r];    // denom, row-aligned w/ acc
      tw[(q * 4 + r) * 33 + li]      = acc[pb][0][r] * inv;
      tw[(q * 4 + r) * 33 + 16 + li] = acc[pb][1][r] * inv;
    }
    // same-wave RAW through LDS (wave owns tw); lgkmcnt ordering suffices
#pragma unroll
    for (int s2 = 0; s2 < 8; ++s2) {
      const int i = s2 * 4 + q;
      ob[(size_t)i * HW + pb * 16 + li] = tw[li * 33 + i];  // 64B segments
    }
  }
}

extern "C" void kernel_launch(void* const* d_in, const int* in_sizes, int n_in,
                              void* d_out, int out_size, void* d_ws, size_t ws_size,
                              hipStream_t stream) {
  const float* x   = (const float*)d_in[0];
  const float* wk  = (const float*)d_in[1];
  const float* bk  = (const float*)d_in[2];
  const float* mem = (const float*)d_in[3];

  unsigned short* wfragP = (unsigned short*)d_ws;                     // 65,536 B
  unsigned short* mfragP = (unsigned short*)((char*)d_ws + 65536);    // 147,456 B

  static int attr_set = 0;   // idempotent runtime attr (not a stream op)
  if (!attr_set) {
    hipFuncSetAttribute((const void*)fused_kernel,
                        hipFuncAttributeMaxDynamicSharedMemorySize, SMEM_BYTES);
    attr_set = 1;
  }

  wfragP_prep<<<dim3(16), dim3(256), 0, stream>>>(wk, wfragP);
  mfragP_prep<<<dim3(36), dim3(256), 0, stream>>>(mem, mfragP);
  fused_kernel<<<dim3(512), dim3(512), SMEM_BYTES, stream>>>(
      x, wfragP, mfragP, bk, (float*)d_out);
}

// Round 8
// 94.686 us; speedup vs baseline: 3.7862x; 1.0735x over previous
//
#include <hip/hip_runtime.h>
#include <hip/hip_bf16.h>

// Problem constants
#define B_   8
#define CIN  128
#define CKEY 256   // N_HEADS*HEAD_DIM key channels
#define NH   8
#define HOUT 32    // OUT_CH / N_HEADS
#define CPH  288   // softmax length per head
#define HW   4096

// LDS geometry
#define ESTR   264                 // E2 x-stride in bf16 (132 dw; 16B-aligned blocks)
#define EROW   (66 * ESTR)         // 17424 elems per y-row
#define E2_BYTES   (4 * EROW * 2)            // 139392 (rows h0-1..h0+2)
#define XBUF_BYTES (64 * 136 * 2)            // 17408 (68 dw per px, swizzled)
#define SMEM_BYTES (E2_BYTES + XBUF_BYTES)   // 156800 <= 160 KiB

typedef __attribute__((ext_vector_type(8))) short bf16x8;
typedef __attribute__((ext_vector_type(4))) float f32x4;

__device__ __forceinline__ unsigned bfpack2(float a, float b) {  // RNE pair
  __hip_bfloat162 h = __float22bfloat162_rn(float2{a, b});
  unsigned r;
  __builtin_memcpy(&r, &h, 4);
  return r;
}
__device__ __forceinline__ unsigned short f2bf(float f) {
  unsigned u = __builtin_bit_cast(unsigned, f);
  u += 0x7FFFu + ((u >> 16) & 1u);
  return (unsigned short)(u >> 16);
}

// ---------------------------------------------------------------------------
// Merged prep: blocks 0..15 pack W A-frags (permuted och: tile (cm,sh),
// m-idx li -> och = cm + 8*(sh*16+li), k -> ic = ks*32+q*8+j).
// Blocks 16..51 pack memory B-frags reindexed by (m,p,s):
// c = ((m-p)&7)+8s, t = (9c+p)>>3; n = li -> i = ib*16+li, k = q*8+j -> s.
// ---------------------------------------------------------------------------
__global__ __launch_bounds__(256) void prep_kernel(
    const float* __restrict__ wk, const float* __restrict__ mem,
    unsigned short* __restrict__ wfragP, unsigned short* __restrict__ mfragP)
{
  const int gb = blockIdx.x;
  if (gb < 16) {
    const int idx  = gb * 256 + threadIdx.x;   // 0..4095
    const int lane = idx & 63, fi = idx >> 6;
    const int ks = fi & 3, sh = (fi >> 2) & 1, cm = fi >> 3;
    const int li = lane & 15, q = lane >> 4;
    const int och = cm + 8 * (sh * 16 + li);
    const int ic0 = ks * 32 + q * 8;
    unsigned short* dst = wfragP + (size_t)idx * 8;
#pragma unroll
    for (int j = 0; j < 8; ++j) dst[j] = f2bf(wk[och * CIN + ic0 + j]);
  } else {
    const int idx  = (gb - 16) * 256 + threadIdx.x;  // 0..9215
    const int lane = idx & 63, fi = idx >> 6;        // 0..143
    const int ib = fi & 1, pm = fi >> 1;
    const int p = pm % 9, m = pm / 9;
    const int li = lane & 15, q = lane >> 4;
    const int i  = ib * 16 + li;
    unsigned short* dst = mfragP + (size_t)idx * 8;
#pragma unroll
    for (int j = 0; j < 8; ++j) {
      const int s = q * 8 + j;
      const int c = ((m - p + 8) & 7) + 8 * s;
      const int t = (9 * c + p) >> 3;
      dst[j] = f2bf(mem[(m * CPH + t) * HOUT + i]);
    }
  }
}

// ---------------------------------------------------------------------------
// Fused conv + softmax + matvec, h-PAIR per block.
// grid = 256 (b = bid&7 XCD swizzle, hp = bid>>3, h0 = 2*hp) = 1 block/CU.
// Phases:
//  0) issue ALL x global loads (4 rows h0-1..h0+2, packed bf16 in VGPRs)
//  1) per row: ds_write xbuf -> sync -> conv MFMA + exp -> E2 row -> sync
//     (wave = cm-class; borders = 1.0 = exp(0))
//  2) attn per hh in {0,1}: wave = head m; per (p,pb): one ds_read_b128
//     A-frag from E2; 3 MFMA (2 out-cols + ones-B denominator, row-aligned)
//  3) epilogue per hh: scale by 1/denom, per-wave LDS transpose, wide store
// ---------------------------------------------------------------------------
__global__ __launch_bounds__(512, 2) void fused_kernel(
    const float* __restrict__ x, const unsigned short* __restrict__ wfragP,
    const unsigned short* __restrict__ mfragP, const float* __restrict__ bk,
    float* __restrict__ out)
{
  extern __shared__ char smem[];
  unsigned short* e2 = (unsigned short*)smem;
  unsigned*       xdw = (unsigned*)(smem + E2_BYTES);       // xbuf, 68 dw/px
  float*          tileb = (float*)(smem + E2_BYTES);        // epilogue reuse

  const int tid = threadIdx.x;
  const int bid = blockIdx.x;
  const int b  = bid & 7;                   // XCD swizzle: batch per XCD
  const int h0 = (bid >> 3) * 2;
  const int lane = tid & 63;
  const int wv = __builtin_amdgcn_readfirstlane(tid >> 6);
  const int li = lane & 15, q = lane >> 4;

  // ---- bias, permuted: tile (cm=wv, sh), row r -> och = wv + 8*(sh*16+4q+r)
  float bias[2][4];
#pragma unroll
  for (int sh = 0; sh < 2; ++sh)
#pragma unroll
    for (int r = 0; r < 4; ++r)
      bias[sh][r] = bk[wv + 8 * (sh * 16 + 4 * q + r)];

  // ================= phase 0: all x loads up-front =================
  const int spx = tid & 63, sicg = tid >> 6;
  const int sxor = ((spx >> 3) & 7) << 3;   // 16B-block bank swizzle

  const bool valid[4] = {h0 - 1 >= 0, true, true, h0 + 2 < 64};
  unsigned pk[4][8];
#pragma unroll
  for (int r = 0; r < 4; ++r) {
    if (!valid[r]) continue;
    const int y = h0 - 1 + r;
    const float* xr = x + (size_t)b * CIN * HW + y * 64 + spx;
#pragma unroll
    for (int r4 = 0; r4 < 4; ++r4) {
      const int ic0 = 4 * sicg + 32 * r4;
      const float v0 = xr[(size_t)(ic0 + 0) * HW];   // 256B coalesced each
      const float v1 = xr[(size_t)(ic0 + 1) * HW];
      const float v2 = xr[(size_t)(ic0 + 2) * HW];
      const float v3 = xr[(size_t)(ic0 + 3) * HW];
      pk[r][2 * r4 + 0] = bfpack2(v0, v1);
      pk[r][2 * r4 + 1] = bfpack2(v2, v3);
    }
  }

  // out-of-range rows -> exp(0) = 1.0 everywhere (before first sync)
#pragma unroll
  for (int r = 0; r < 4; r += 3) {
    if (!valid[r]) {
      unsigned* erow = (unsigned*)(e2 + r * EROW);
      for (int d = tid; d < 66 * 132; d += 512) erow[d] = 0x3F803F80u;
    }
  }

  // ================= phase 1: conv rows =================
#pragma unroll
  for (int rr = 0; rr < 4; ++rr) {
    if (valid[rr]) {
#pragma unroll
      for (int r4 = 0; r4 < 4; ++r4) {
        const int o = (2 * sicg + 16 * r4) ^ sxor;
        *(uint2*)(xdw + spx * 68 + o) = make_uint2(pk[rr][2 * r4], pk[rr][2 * r4 + 1]);
      }
    }
    __syncthreads();
    if (valid[rr]) {
      f32x4 acc[2][4];                      // [sh][pt]
#pragma unroll
      for (int sh = 0; sh < 2; ++sh)
#pragma unroll
        for (int pt = 0; pt < 4; ++pt) {
          f32x4 cv; cv[0] = bias[sh][0]; cv[1] = bias[sh][1];
          cv[2] = bias[sh][2]; cv[3] = bias[sh][3];
          acc[sh][pt] = cv;
        }
#pragma unroll
      for (int ks = 0; ks < 4; ++ks) {
        const bf16x8 a0 = *(const bf16x8*)(
            wfragP + ((size_t)(((wv * 2 + 0) * 4 + ks) * 64 + lane)) * 8);
        const bf16x8 a1 = *(const bf16x8*)(
            wfragP + ((size_t)(((wv * 2 + 1) * 4 + ks) * 64 + lane)) * 8);
#pragma unroll
        for (int pt = 0; pt < 4; ++pt) {
          const int px  = pt * 16 + li;
          const int blk = (ks * 16 + q * 4) ^ (((px >> 3) & 7) << 3);
          const bf16x8 bfr = *(const bf16x8*)(xdw + px * 68 + blk);
          acc[0][pt] = __builtin_amdgcn_mfma_f32_16x16x32_bf16(a0, bfr, acc[0][pt], 0, 0, 0);
          acc[1][pt] = __builtin_amdgcn_mfma_f32_16x16x32_bf16(a1, bfr, acc[1][pt], 0, 0, 0);
        }
      }
      // exp + E2 write: lane's 4 s-values contiguous -> b64
      unsigned short* erow = e2 + rr * EROW;
#pragma unroll
      for (int sh = 0; sh < 2; ++sh)
#pragma unroll
        for (int pt = 0; pt < 4; ++pt) {
          const float w0 = __expf(acc[sh][pt][0]);
          const float w1 = __expf(acc[sh][pt][1]);
          const float w2 = __expf(acc[sh][pt][2]);
          const float w3 = __expf(acc[sh][pt][3]);
          unsigned short* dst = erow + (pt * 16 + li + 1) * ESTR
                              + wv * 32 + sh * 16 + 4 * q;
          *(uint2*)dst = make_uint2(bfpack2(w0, w1), bfpack2(w2, w3));
        }
      if (tid < 256) {                      // x-borders = exp(0) = 1.0
        const int xcol = (tid & 1) ? 65 : 0;
        ((unsigned*)(erow + xcol * ESTR))[tid >> 1] = 0x3F803F80u;
      }
    }
    __syncthreads();
  }

  // ================= phase 2+3: attention per h =================
  const int m = wv;                         // wave = head
  const unsigned short* mf = mfragP + (size_t)(m * 9) * 2 * 64 * 8;
  const int4 onesi = make_int4(0x3F803F80, 0x3F803F80, 0x3F803F80, 0x3F803F80);
  const bf16x8 bones = __builtin_bit_cast(bf16x8, onesi);
  float* tw = tileb + wv * (16 * 33);       // per-wave transpose scratch

#pragma unroll
  for (int hh = 0; hh < 2; ++hh) {
    f32x4 acc[4][2], accs[4];
#pragma unroll
    for (int pb = 0; pb < 4; ++pb) {
      acc[pb][0] = {0.f, 0.f, 0.f, 0.f};
      acc[pb][1] = {0.f, 0.f, 0.f, 0.f};
      accs[pb]   = {0.f, 0.f, 0.f, 0.f};
    }
#pragma unroll
    for (int p = 0; p < 9; ++p) {
      const bf16x8 bm0 = *(const bf16x8*)(mf + ((size_t)((p * 2 + 0) * 64 + lane)) * 8);
      const bf16x8 bm1 = *(const bf16x8*)(mf + ((size_t)((p * 2 + 1) * 64 + lane)) * 8);
      const int cm   = (m - p + 8) & 7;
      const int rrow = hh + p / 3;
      const int dxp  = p - 3 * (p / 3);
      const unsigned short* abase = e2 + rrow * EROW + (li + dxp) * ESTR
                                  + cm * 32 + q * 8;
#pragma unroll
      for (int pb = 0; pb < 4; ++pb) {
        const bf16x8 af = *(const bf16x8*)(abase + pb * 16 * ESTR);  // b128
        acc[pb][0] = __builtin_amdgcn_mfma_f32_16x16x32_bf16(af, bm0, acc[pb][0], 0, 0, 0);
        acc[pb][1] = __builtin_amdgcn_mfma_f32_16x16x32_bf16(af, bm1, acc[pb][1], 0, 0, 0);
        accs[pb]   = __builtin_amdgcn_mfma_f32_16x16x32_bf16(af, bones, accs[pb], 0, 0, 0);
      }
    }
    float* ob = out + ((size_t)(b * CKEY + m * HOUT)) * HW + (h0 + hh) * 64;
#pragma unroll
    for (int pb = 0; pb < 4; ++pb) {
#pragma unroll
      for (int r = 0; r < 4; ++r) {
        const float inv = 1.0f / accs[pb][r];    // denom row-aligned w/ acc
        tw[(q * 4 + r) * 33 + li]      = acc[pb][0][r] * inv;
        tw[(q * 4 + r) * 33 + 16 + li] = acc[pb][1][r] * inv;
      }
      // same-wave RAW through LDS (wave owns tw); lgkmcnt ordering suffices
#pragma unroll
      for (int s2 = 0; s2 < 8; ++s2) {
        const int i = s2 * 4 + q;
        ob[(size_t)i * HW + pb * 16 + li] = tw[li * 33 + i];  // 64B segments
      }
    }
  }
}

extern "C" void kernel_launch(void* const* d_in, const int* in_sizes, int n_in,
                              void* d_out, int out_size, void* d_ws, size_t ws_size,
                              hipStream_t stream) {
  const float* x   = (const float*)d_in[0];
  const float* wk  = (const float*)d_in[1];
  const float* bk  = (const float*)d_in[2];
  const float* mem = (const float*)d_in[3];

  unsigned short* wfragP = (unsigned short*)d_ws;                     // 65,536 B
  unsigned short* mfragP = (unsigned short*)((char*)d_ws + 65536);    // 147,456 B

  (void)hipFuncSetAttribute((const void*)fused_kernel,
                            hipFuncAttributeMaxDynamicSharedMemorySize, SMEM_BYTES);

  prep_kernel<<<dim3(52), dim3(256), 0, stream>>>(wk, mem, wfragP, mfragP);
  fused_kernel<<<dim3(256), dim3(512), SMEM_BYTES, stream>>>(
      x, wfragP, mfragP, bk, (float*)d_out);
}